// Round 4
// baseline (213.574 us; speedup 1.0000x reference)
//
#include <hip/hip_runtime.h>
#include <math.h>

// TrxMeanEncoder fused kernel for MI355X (gfx950) — round 3 (resubmit; R3
// never ran: GPU acquisition timeout).
//
// out[b] = concat( hist(mcc[b])/1024  (W_mcc = I, folded),
//                  hist(trx[b])/1024  (W_trx = I, folded),
//                  mean_{t<L} log1p(|a|)*sign(a) )
//
// Round-3 change: persistent waves, 4 rows/wave, register double-buffered
// prefetch of the next row's 12x16B loads while the current row's
// atomics/log/reduce/store run. Attacks per-row cold-start load latency,
// which round 2 isolated as the remaining suspect (VALU 8%, BW 21%,
// DS-pipe accounting ~6 us, yet dur invariant at 79 us across R1/R2).

constexpr int kB        = 16384;
constexpr int kT        = 1024;
constexpr int kVmcc     = 400;
constexpr int kNout     = 501;
constexpr int kThreads  = 256;   // 4 waves
constexpr int kRowsPerW = 4;     // rows per wave (register-pipelined)
constexpr int kHStride  = 512;   // u32 per wave histogram (500 used)

// 4-float store with only 4B alignment guaranteed (row stride 2004 B).
struct __attribute__((aligned(4))) f4a { float x, y, z, w; };

__global__ __launch_bounds__(kThreads) void trx_mean_encoder(
    const int* __restrict__ mcc, const int* __restrict__ trx,
    const float* __restrict__ amount, const int* __restrict__ seq_lens,
    float* __restrict__ out)
{
  __shared__ unsigned int hist[4 * kHStride];  // 8 KB (one slice per wave)

  const int tid  = threadIdx.x;
  const int wid  = tid >> 6;
  const int lane = tid & 63;
  // Wave owns kRowsPerW consecutive rows.
  const int row0 = (blockIdx.x * 4 + wid) * kRowsPerW;

  unsigned int* h = hist + wid * kHStride;  // [0,400) mcc, [400,500) trx
  const float inv_t = 1.0f / (float)kT;
  constexpr float kLn2 = 0.69314718055994531f;

  auto LOAD = [&](int r, int4 (&m)[4], int4 (&t)[4], float4 (&a)[4], int& L) {
    const size_t  off = (size_t)r * kT;
    const int4*   m4p = reinterpret_cast<const int4*>(mcc + off);
    const int4*   t4p = reinterpret_cast<const int4*>(trx + off);
    const float4* a4p = reinterpret_cast<const float4*>(amount + off);
#pragma unroll
    for (int k = 0; k < 4; ++k) {
      m[k] = m4p[lane + 64 * k];
      t[k] = t4p[lane + 64 * k];
      a[k] = a4p[lane + 64 * k];
    }
    L = seq_lens[r];
  };

  auto PROC = [&](int r, int4 (&m)[4], int4 (&t)[4], float4 (&a)[4], int L) {
    // Zero this wave's histogram (same-wave DS ordering: the previous row's
    // readback DS ops complete before these writes land).
    const uint4 z = make_uint4(0u, 0u, 0u, 0u);
    reinterpret_cast<uint4*>(h)[lane]      = z;
    reinterpret_cast<uint4*>(h)[lane + 64] = z;

    float s = 0.0f;
#pragma unroll
    for (int k = 0; k < 4; ++k) {
      atomicAdd(&h[m[k].x], 1u);
      atomicAdd(&h[m[k].y], 1u);
      atomicAdd(&h[m[k].z], 1u);
      atomicAdd(&h[m[k].w], 1u);
      atomicAdd(&h[kVmcc + t[k].x], 1u);
      atomicAdd(&h[kVmcc + t[k].y], 1u);
      atomicAdd(&h[kVmcc + t[k].z], 1u);
      atomicAdd(&h[kVmcc + t[k].w], 1u);

      const int   base  = 4 * (lane + 64 * k);
      const float av[4] = {a[k].x, a[k].y, a[k].z, a[k].w};
#pragma unroll
      for (int j = 0; j < 4; ++j) {
        const float x = av[j];
        const float v = __log2f(1.0f + fabsf(x)) * kLn2;  // log1p(|x|)
        s += (base + j < L) ? copysignf(v, x) : 0.0f;
      }
    }

    // Wave-wide butterfly sum.
#pragma unroll
    for (int off = 32; off; off >>= 1) s += __shfl_xor(s, off, 64);

    // Drain this wave's DS atomics before reading counts back.
    asm volatile("s_waitcnt lgkmcnt(0)" ::: "memory");

    float* orow = out + (size_t)r * kNout;
#pragma unroll
    for (int k = 0; k < 2; ++k) {
      const int v4 = lane + 64 * k;  // 4-count group index
      if (v4 < 125) {                // 125*4 = 500 counts
        const uint4 c = reinterpret_cast<const uint4*>(h)[v4];
        f4a o;
        o.x = (float)c.x * inv_t;
        o.y = (float)c.y * inv_t;
        o.z = (float)c.z * inv_t;
        o.w = (float)c.w * inv_t;
        *reinterpret_cast<f4a*>(orow + 4 * v4) = o;
      }
    }
    if (lane == 0) orow[kNout - 1] = s / (float)L;
  };

  // Register double-buffer: A/B named sets, compile-time selected (rule #20).
  int4 mA[4], tA[4], mB[4], tB[4];
  float4 aA[4], aB[4];
  int LA, LB;

  LOAD(row0, mA, tA, aA, LA);
#pragma unroll
  for (int i = 0; i < kRowsPerW; ++i) {
    if (i & 1) {
      if (i + 1 < kRowsPerW) LOAD(row0 + i + 1, mA, tA, aA, LA);
      PROC(row0 + i, mB, tB, aB, LB);
    } else {
      if (i + 1 < kRowsPerW) LOAD(row0 + i + 1, mB, tB, aB, LB);
      PROC(row0 + i, mA, tA, aA, LA);
    }
  }
}

extern "C" void kernel_launch(void* const* d_in, const int* in_sizes, int n_in,
                              void* d_out, int out_size, void* d_ws, size_t ws_size,
                              hipStream_t stream) {
  const int*   mcc      = (const int*)d_in[0];
  const int*   trx      = (const int*)d_in[1];
  const float* amount   = (const float*)d_in[2];
  const int*   seq_lens = (const int*)d_in[3];
  // d_in[4] (W_mcc) and d_in[5] (W_trx) are identity matrices -> folded.
  (void)in_sizes; (void)n_in; (void)d_ws; (void)ws_size; (void)out_size;

  trx_mean_encoder<<<dim3(kB / (4 * kRowsPerW)), dim3(kThreads), 0, stream>>>(
      mcc, trx, amount, seq_lens, (float*)d_out);
}

// Round 5
// 211.417 us; speedup vs baseline: 1.0102x; 1.0102x over previous
//
#include <hip/hip_runtime.h>
#include <math.h>

// TrxMeanEncoder fused kernel for MI355X (gfx950) — round 5.
//
// out[b] = concat( hist(mcc[b])/1024  (W_mcc = I, folded),
//                  hist(trx[b])/1024  (W_trx = I, folded),
//                  mean_{t<L} log1p(|a|)*sign(a) )
//
// R1/R2/R4 all land at 79-86us with VALU<=8%, HBM ~20%, occupancy 23..63%,
// and bit-identical SQ_LDS_BANK_CONFLICT — the DS pipe running 524K
// histogram atomics is the saturated resource. Round-5 attack: sub-wave
// REPLICATED histograms in BANK-DISJOINT sets: 16-lane group g updates its
// own replica living entirely in banks [8g, 8g+8):
//     word(bin, g) = (bin>>3)*32 + 8*g + (bin&7)      (bank = 8g + bin&7)
// This cuts per-instruction serialization (16 lanes over 8 private banks,
// same-address dupes ~eliminated) if the atomic cost is conflict-driven.
// Readback sums the 4 replicas (g-staggered -> conflict-free) and stores
// fully-coalesced scalar dwords (bin = lane + 64k).

constexpr int kB        = 16384;
constexpr int kT        = 1024;
constexpr int kVmcc     = 400;
constexpr int kNout     = 501;
constexpr int kThreads  = 256;    // 4 waves, 1 row per wave
constexpr int kHWords   = 2048;   // u32 words per wave (mcc 1600 + trx 416, padded)
constexpr int kTrxBase  = 1600;   // word offset of trx region (multiple of 32)

__global__ __launch_bounds__(kThreads) void trx_mean_encoder(
    const int* __restrict__ mcc, const int* __restrict__ trx,
    const float* __restrict__ amount, const int* __restrict__ seq_lens,
    float* __restrict__ out)
{
  __shared__ unsigned int hist[4 * kHWords];  // 32 KB (one slice per wave)

  const int tid  = threadIdx.x;
  const int wid  = tid >> 6;
  const int lane = tid & 63;
  const int row  = blockIdx.x * 4 + wid;

  unsigned int* h = hist + wid * kHWords;
  const int grp8 = (lane >> 4) << 3;  // this lane's replica bank-base (0,8,16,24)

  // Zero all 2048 words: 8 x ds_write_b128 per lane (same-wave DS ordering
  // guarantees zeros land before our atomics; validated in R2).
  const uint4 z = make_uint4(0u, 0u, 0u, 0u);
#pragma unroll
  for (int k = 0; k < 8; ++k)
    reinterpret_cast<uint4*>(h)[lane + 64 * k] = z;

  const size_t  rowoff = (size_t)row * kT;
  const int4*   m4p = reinterpret_cast<const int4*>(mcc + rowoff);
  const int4*   t4p = reinterpret_cast<const int4*>(trx + rowoff);
  const float4* a4p = reinterpret_cast<const float4*>(amount + rowoff);

  // 16 tokens/lane: 12 coalesced 16B loads, issued up front.
  int4 m[4], t[4]; float4 a[4];
#pragma unroll
  for (int k = 0; k < 4; ++k) {
    m[k] = m4p[lane + 64 * k];
    t[k] = t4p[lane + 64 * k];
    a[k] = a4p[lane + 64 * k];
  }
  const int L = seq_lens[row];  // wave-uniform -> scalar load

  // Replica-local word index: bank = 8*g + (bin&7)  (group-private banks).
  auto MW = [&](int bin) { return ((bin >> 3) << 5) + grp8 + (bin & 7); };
  auto TW = [&](int bin) { return kTrxBase + ((bin >> 3) << 5) + grp8 + (bin & 7); };

  constexpr float kLn2 = 0.69314718055994531f;
  float s = 0.0f;
#pragma unroll
  for (int k = 0; k < 4; ++k) {
    atomicAdd(&h[MW(m[k].x)], 1u);
    atomicAdd(&h[MW(m[k].y)], 1u);
    atomicAdd(&h[MW(m[k].z)], 1u);
    atomicAdd(&h[MW(m[k].w)], 1u);
    atomicAdd(&h[TW(t[k].x)], 1u);
    atomicAdd(&h[TW(t[k].y)], 1u);
    atomicAdd(&h[TW(t[k].z)], 1u);
    atomicAdd(&h[TW(t[k].w)], 1u);

    const int   base  = 4 * (lane + 64 * k);
    const float av[4] = {a[k].x, a[k].y, a[k].z, a[k].w};
#pragma unroll
    for (int j = 0; j < 4; ++j) {
      const float x = av[j];
      const float v = __log2f(1.0f + fabsf(x)) * kLn2;  // log1p(|x|)
      s += (base + j < L) ? copysignf(v, x) : 0.0f;
    }
  }

  // Wave-wide butterfly sum.
#pragma unroll
  for (int off = 32; off; off >>= 1) s += __shfl_xor(s, off, 64);

  // Drain this wave's DS atomics before reading counts back.
  asm volatile("s_waitcnt lgkmcnt(0)" ::: "memory");

  const float inv_t = 1.0f / (float)kT;
  float* orow = out + (size_t)row * kNout;

  // Readback: bin v = lane + 64k, sum 4 replicas with g staggered per
  // 8-lane group so each 32-lane half covers all 32 banks each round.
#pragma unroll
  for (int k = 0; k < 8; ++k) {
    const int v = lane + 64 * k;
    if (v < 500) {
      const int  bin  = (v < kVmcc) ? v : (v - kVmcc);
      const int  base = (v < kVmcc) ? 0 : kTrxBase;
      const int  wrd  = base + ((bin >> 3) << 5) + (bin & 7);
      unsigned int c = 0;
#pragma unroll
      for (int j = 0; j < 4; ++j) {
        const int g = ((lane >> 3) + j) & 3;
        c += h[wrd + (g << 3)];
      }
      orow[v] = (float)c * inv_t;  // coalesced dword store
    }
  }
  if (lane == 0) orow[kNout - 1] = s / (float)L;
}

extern "C" void kernel_launch(void* const* d_in, const int* in_sizes, int n_in,
                              void* d_out, int out_size, void* d_ws, size_t ws_size,
                              hipStream_t stream) {
  const int*   mcc      = (const int*)d_in[0];
  const int*   trx      = (const int*)d_in[1];
  const float* amount   = (const float*)d_in[2];
  const int*   seq_lens = (const int*)d_in[3];
  // d_in[4] (W_mcc) and d_in[5] (W_trx) are identity matrices -> folded.
  (void)in_sizes; (void)n_in; (void)d_ws; (void)ws_size; (void)out_size;

  trx_mean_encoder<<<dim3(kB / 4), dim3(kThreads), 0, stream>>>(
      mcc, trx, amount, seq_lens, (float*)d_out);
}